// Round 5
// baseline (243.721 us; speedup 1.0000x reference)
//
#include <hip/hip_runtime.h>
#include <hip/hip_bf16.h>

#define NROW 4096
#define D 128
#define TOT 8192
#define PRESCALE 1.69864407f  // sqrt(2*log2(e)): acc = logit * log2(e)
#define LN2 0.69314718055994531f
#define GRID_G 1024
#define NP 4  // phases: 4 x 64 cols = 256 cols per block

typedef __attribute__((ext_vector_type(8))) short bf16x8;
typedef __attribute__((ext_vector_type(4))) float f32x4;

static __device__ __forceinline__ float fast_exp2(float x) {
  return __builtin_amdgcn_exp2f(x);
}
static __device__ __forceinline__ float fast_log2(float x) {
  return __builtin_amdgcn_logf(x);
}
static __device__ __forceinline__ unsigned short f2bf(float x) {
  unsigned u = __float_as_uint(x);
  return (unsigned short)((u + 0x7fffu + ((u >> 16) & 1u)) >> 16);
}
static __device__ __forceinline__ void gload16(const void* g, void* l) {
  __builtin_amdgcn_global_load_lds(
      (const __attribute__((address_space(1))) unsigned int*)g,
      (__attribute__((address_space(3))) unsigned int*)l, 16, 0, 0);
}

// Kernel 1: normalize -> prescaled bf16 Z; exact fp32 pos logits; zero
// rowsum + completion counter. (Correct in rounds 1-2; unchanged.)
__global__ __launch_bounds__(256) void k_norm(
    const float* __restrict__ ei, const float* __restrict__ ej,
    unsigned short* __restrict__ Zp, float* __restrict__ pos,
    float* __restrict__ rowsum, unsigned* __restrict__ ctr) {
  int gid = blockIdx.x * 256 + (int)threadIdx.x;
  if (gid < TOT) rowsum[gid] = 0.0f;
  if (gid == TOT) *ctr = 0u;

  int wid = threadIdx.x >> 6;
  int lane = threadIdx.x & 63;
  int r = blockIdx.x * 4 + wid;
  const float2 xi = *(const float2*)(ei + (size_t)r * D + lane * 2);
  const float2 xj = *(const float2*)(ej + (size_t)r * D + lane * 2);
  float si = xi.x * xi.x + xi.y * xi.y;
  float sj = xj.x * xj.x + xj.y * xj.y;
  float dd = xi.x * xj.x + xi.y * xj.y;
#pragma unroll
  for (int m = 32; m >= 1; m >>= 1) {
    si += __shfl_xor(si, m, 64);
    sj += __shfl_xor(sj, m, 64);
    dd += __shfl_xor(dd, m, 64);
  }
  float ri = rsqrtf(si); ri = ri * (1.5f - 0.5f * si * ri * ri);
  float rj = rsqrtf(sj); rj = rj * (1.5f - 0.5f * sj * rj * rj);
  ((unsigned*)(Zp + (size_t)r * D))[lane] =
      (unsigned)f2bf(xi.x * ri * PRESCALE) | ((unsigned)f2bf(xi.y * ri * PRESCALE) << 16);
  ((unsigned*)(Zp + (size_t)(r + NROW) * D))[lane] =
      (unsigned)f2bf(xj.x * rj * PRESCALE) | ((unsigned)f2bf(xj.y * rj * PRESCALE) << 16);
  if (lane == 0) pos[r] = 2.0f * dd * ri * rj;
}

// Kernel 2: fused Z*Z^T + exp + rowsum; last block folds the final loss.
// 1024 blocks = 32 row-groups x 32 col-slices (XCD-pinned), 4 waves/block,
// wave = 64 rows (A in registers). 4 phases x 64 cols, ring-2 LDS (2x16KB),
// T3 schedule: STAGE(p+1) first, compute phase p covers its latency, one
// vmcnt(0)+barrier per phase. Full 4-bit XOR swizzle on B tiles.
__global__ __launch_bounds__(256, 4) void k_gemm(
    const unsigned short* __restrict__ Zp, float* __restrict__ rowsum,
    const float* __restrict__ pos, unsigned* __restrict__ ctr,
    float* __restrict__ out) {
  __shared__ __align__(16) char ldsb[32768];
  const int tid = (int)threadIdx.x;
  const int wid = tid >> 6, lane = tid & 63;
  const int lo = lane & 15, hi = lane >> 4;
  const int b = (int)blockIdx.x;
  const int cs = (b & 7) * 4 + ((b >> 3) & 3);  // col-slice 0..31, XCD-pinned
  const int rb = b >> 5;                        // row-group 0..31
  const int rowbase = rb * 256 + wid * 64;
  const int RT0 = rb * 16 + wid * 4;            // wave's first 16-row tile

  // A fragments: 64 rows x 128 k per wave (64 VGPR), held throughout
  bf16x8 af[4][4];
#pragma unroll
  for (int g = 0; g < 4; ++g) {
    const unsigned short* za = Zp + (size_t)(rowbase + g * 16 + lo) * D + hi * 8;
#pragma unroll
    for (int kk = 0; kk < 4; ++kk) af[g][kk] = *(const bf16x8*)(za + kk * 32);
  }

  // staging: LDS[row][c] = G[row][c ^ ((row&15)<<4)], linear LDS dest
  const char* zb = (const char*)Zp + (size_t)cs * 65536;  // cs*256 rows
  int goff[4];
#pragma unroll
  for (int q = 0; q < 4; ++q) {
    int row = wid * 16 + q * 4 + hi;  // LDS row 0..63 within phase tile
    goff[q] = row * 256 + ((lo * 16) ^ ((row & 15) << 4));
  }
  // read: subtile st, B-row st*16+lo, chunk (kk*4+hi)*16, same XOR (row&15==lo)
  int rdo[4];
#pragma unroll
  for (int kk = 0; kk < 4; ++kk)
    rdo[kk] = lo * 256 + (((kk * 4 + hi) * 16) ^ (lo << 4));

  float sums[4][4];
#pragma unroll
  for (int g = 0; g < 4; ++g)
#pragma unroll
    for (int r = 0; r < 4; ++r) sums[g][r] = 0.0f;

#define STAGE(pp, buf)                                                \
  do {                                                                \
    char* ld_ = ldsb + (buf) * 16384 + wid * 4096;                    \
    const char* gp_ = zb + (size_t)(pp) * 16384;                      \
    gload16(gp_ + goff[0], ld_);                                      \
    gload16(gp_ + goff[1], ld_ + 1024);                               \
    gload16(gp_ + goff[2], ld_ + 2048);                               \
    gload16(gp_ + goff[3], ld_ + 3072);                               \
  } while (0)

  // prologue: stage phase 0 (A loads also drain here)
  STAGE(0, 0);
  asm volatile("s_waitcnt vmcnt(0)" ::: "memory");
  __builtin_amdgcn_s_barrier();

#pragma unroll
  for (int p = 0; p < NP; ++p) {
    const int cur = p & 1;
    if (p + 1 < NP) STAGE(p + 1, cur ^ 1);  // prefetch under this phase's compute
#pragma unroll
    for (int st = 0; st < 4; ++st) {
      const char* sb = ldsb + cur * 16384 + st * 4096;
      f32x4 acc[4];
#pragma unroll
      for (int g = 0; g < 4; ++g) acc[g] = (f32x4){0.f, 0.f, 0.f, 0.f};
      __builtin_amdgcn_s_setprio(1);
#pragma unroll
      for (int kk = 0; kk < 4; ++kk) {
        bf16x8 bv = *(const bf16x8*)(sb + rdo[kk]);
#pragma unroll
        for (int g = 0; g < 4; ++g)
          acc[g] = __builtin_amdgcn_mfma_f32_16x16x32_bf16(af[g][kk], bv, acc[g], 0, 0, 0);
      }
      __builtin_amdgcn_s_setprio(0);
      const int gd = cs * 16 + p * 4 + st - RT0;  // diag subtile's g (uniform)
#pragma unroll
      for (int g = 0; g < 4; ++g)
#pragma unroll
        for (int r = 0; r < 4; ++r) {
          float e = fast_exp2(acc[g][r]);
          if (g == gd && lo == hi * 4 + r) e = 0.0f;  // mask self
          sums[g][r] += e;
        }
    }
    asm volatile("s_waitcnt vmcnt(0)" ::: "memory");  // prefetch landed
    __builtin_amdgcn_s_barrier();                     // visible to all waves
  }
#undef STAGE

  // reduce 16 column-slots per row; one atomic per row per wave
#pragma unroll
  for (int g = 0; g < 4; ++g)
#pragma unroll
    for (int r = 0; r < 4; ++r) {
      float v = sums[g][r];
      v += __shfl_xor(v, 1, 64);
      v += __shfl_xor(v, 2, 64);
      v += __shfl_xor(v, 4, 64);
      v += __shfl_xor(v, 8, 64);
      if (lo == 0) atomicAdd(&rowsum[rowbase + g * 16 + hi * 4 + r], v);
    }

  // last-block-done final reduction (proven in round 2)
  __syncthreads();
  __shared__ unsigned slast;
  if (tid == 0) {
    __threadfence();
    slast = atomicAdd(ctr, 1u);
  }
  __syncthreads();
  if (slast == GRID_G - 1) {
    __threadfence();  // acquire side
    float s1 = 0.0f, s2 = 0.0f;
    for (int k = tid; k < TOT; k += 256)
      s1 += fast_log2(__hip_atomic_load(&rowsum[k], __ATOMIC_RELAXED,
                                        __HIP_MEMORY_SCOPE_AGENT));
    for (int k = tid; k < NROW; k += 256) s2 += pos[k];
    float c = s1 * (LN2 / (float)TOT) - s2 * (1.0f / (float)NROW);
#pragma unroll
    for (int m = 32; m >= 1; m >>= 1) c += __shfl_xor(c, m, 64);
    __shared__ float ws4[4];
    if (lane == 0) ws4[wid] = c;
    __syncthreads();
    if (tid == 0) out[0] = ws4[0] + ws4[1] + ws4[2] + ws4[3];
  }
}

extern "C" void kernel_launch(void* const* d_in, const int* in_sizes, int n_in,
                              void* d_out, int out_size, void* d_ws, size_t ws_size,
                              hipStream_t stream) {
  const float* ei = (const float*)d_in[0];
  const float* ej = (const float*)d_in[1];
  float* out = (float*)d_out;
  float* rowsum = (float*)d_ws;                                   // 8192 f32
  float* pos = (float*)((char*)d_ws + TOT * 4);                   // 4096 f32
  unsigned* ctr = (unsigned*)((char*)d_ws + TOT * 4 + NROW * 4);  // 1 u32
  unsigned short* Zp =
      (unsigned short*)((char*)d_ws + TOT * 4 + NROW * 4 + 256);  // 8192x128 bf16

  k_norm<<<NROW / 4, 256, 0, stream>>>(ei, ej, Zp, pos, rowsum, ctr);
  k_gemm<<<GRID_G, 256, 0, stream>>>(Zp, rowsum, pos, ctr, out);
}

// Round 7
// 113.975 us; speedup vs baseline: 2.1384x; 2.1384x over previous
//
#include <hip/hip_runtime.h>
#include <hip/hip_bf16.h>

#define NROW 4096
#define D 128
#define TOT 8192
#define PRESCALE 1.69864407f  // sqrt(2*log2(e)): acc = logit * log2(e)
#define LN2 0.69314718055994531f
#define GRID_G 1024
#define NP 4  // phases: 4 x 64 cols = 256 cols per block

typedef __attribute__((ext_vector_type(8))) short bf16x8;
typedef __attribute__((ext_vector_type(4))) float f32x4;

static __device__ __forceinline__ float fast_exp2(float x) {
  return __builtin_amdgcn_exp2f(x);
}
static __device__ __forceinline__ float fast_log2(float x) {
  return __builtin_amdgcn_logf(x);
}
static __device__ __forceinline__ unsigned short f2bf(float x) {
  unsigned u = __float_as_uint(x);
  return (unsigned short)((u + 0x7fffu + ((u >> 16) & 1u)) >> 16);
}
static __device__ __forceinline__ void gload16(const void* g, void* l) {
  __builtin_amdgcn_global_load_lds(
      (const __attribute__((address_space(1))) unsigned int*)g,
      (__attribute__((address_space(3))) unsigned int*)l, 16, 0, 0);
}

// Kernel 1: normalize -> prescaled bf16 Z; exact fp32 pos logits; zero
// rowsum + completion counter. (Proven correct rounds 1-5; unchanged.)
__global__ __launch_bounds__(256) void k_norm(
    const float* __restrict__ ei, const float* __restrict__ ej,
    unsigned short* __restrict__ Zp, float* __restrict__ pos,
    float* __restrict__ rowsum, unsigned* __restrict__ ctr) {
  int gid = blockIdx.x * 256 + (int)threadIdx.x;
  if (gid < TOT) rowsum[gid] = 0.0f;
  if (gid == TOT) *ctr = 0u;

  int wid = threadIdx.x >> 6;
  int lane = threadIdx.x & 63;
  int r = blockIdx.x * 4 + wid;
  const float2 xi = *(const float2*)(ei + (size_t)r * D + lane * 2);
  const float2 xj = *(const float2*)(ej + (size_t)r * D + lane * 2);
  float si = xi.x * xi.x + xi.y * xi.y;
  float sj = xj.x * xj.x + xj.y * xj.y;
  float dd = xi.x * xj.x + xi.y * xj.y;
#pragma unroll
  for (int m = 32; m >= 1; m >>= 1) {
    si += __shfl_xor(si, m, 64);
    sj += __shfl_xor(sj, m, 64);
    dd += __shfl_xor(dd, m, 64);
  }
  float ri = rsqrtf(si); ri = ri * (1.5f - 0.5f * si * ri * ri);
  float rj = rsqrtf(sj); rj = rj * (1.5f - 0.5f * sj * rj * rj);
  ((unsigned*)(Zp + (size_t)r * D))[lane] =
      (unsigned)f2bf(xi.x * ri * PRESCALE) | ((unsigned)f2bf(xi.y * ri * PRESCALE) << 16);
  ((unsigned*)(Zp + (size_t)(r + NROW) * D))[lane] =
      (unsigned)f2bf(xj.x * rj * PRESCALE) | ((unsigned)f2bf(xj.y * rj * PRESCALE) << 16);
  if (lane == 0) pos[r] = 2.0f * dd * ri * rj;
}

// Kernel 2: fused Z*Z^T + exp + rowsum; last block folds the final loss.
// 1024 blocks = 32 row-groups x 32 col-slices (XCD-pinned), 4 waves/block,
// wave = 64 rows (A in registers). 4 phases x 64 cols, ring-2 LDS (2x16KB).
// launch_bounds(256,3): VGPR cap ~170 (need ~140) -> NO SPILL (round-5's
// (256,4)=128 cap spilled af[] -> 400 MB scratch traffic, 4x slowdown).
// #pragma unroll 1 on phase loop keeps live ranges short.
__global__ __launch_bounds__(256, 3) void k_gemm(
    const unsigned short* __restrict__ Zp, float* __restrict__ rowsum,
    const float* __restrict__ pos, unsigned* __restrict__ ctr,
    float* __restrict__ out) {
  __shared__ __align__(16) char ldsb[32768];
  const int tid = (int)threadIdx.x;
  const int wid = tid >> 6, lane = tid & 63;
  const int lo = lane & 15, hi = lane >> 4;
  const int b = (int)blockIdx.x;
  const int cs = (b & 7) * 4 + ((b >> 3) & 3);  // col-slice 0..31, XCD-pinned
  const int rb = b >> 5;                        // row-group 0..31
  const int rowbase = rb * 256 + wid * 64;
  const int RT0 = rb * 16 + wid * 4;            // wave's first 16-row tile

  // A fragments: 64 rows x 128 k per wave (64 regs), held throughout
  bf16x8 af[4][4];
#pragma unroll
  for (int g = 0; g < 4; ++g) {
    const unsigned short* za = Zp + (size_t)(rowbase + g * 16 + lo) * D + hi * 8;
#pragma unroll
    for (int kk = 0; kk < 4; ++kk) af[g][kk] = *(const bf16x8*)(za + kk * 32);
  }

  // staging: LDS[row][c] = G[row][c ^ ((row&15)<<4)], linear LDS dest
  const char* zb = (const char*)Zp + (size_t)cs * 65536;  // cs*256 rows
  int goff[4];
#pragma unroll
  for (int q = 0; q < 4; ++q) {
    int row = wid * 16 + q * 4 + hi;  // LDS row 0..63 within phase tile
    goff[q] = row * 256 + ((lo * 16) ^ ((row & 15) << 4));
  }
  // read: subtile st, B-row st*16+lo, chunk (kk*4+hi)*16, same XOR (row&15==lo)
  int rdo[4];
#pragma unroll
  for (int kk = 0; kk < 4; ++kk)
    rdo[kk] = lo * 256 + (((kk * 4 + hi) * 16) ^ (lo << 4));

  float sums[4][4];
#pragma unroll
  for (int g = 0; g < 4; ++g)
#pragma unroll
    for (int r = 0; r < 4; ++r) sums[g][r] = 0.0f;

#define STAGE(pp, buf)                                                \
  do {                                                                \
    char* ld_ = ldsb + (buf) * 16384 + wid * 4096;                    \
    const char* gp_ = zb + (size_t)(pp) * 16384;                      \
    gload16(gp_ + goff[0], ld_);                                      \
    gload16(gp_ + goff[1], ld_ + 1024);                               \
    gload16(gp_ + goff[2], ld_ + 2048);                               \
    gload16(gp_ + goff[3], ld_ + 3072);                               \
  } while (0)

  // prologue: stage phase 0 (A loads also drain here)
  STAGE(0, 0);
  asm volatile("s_waitcnt vmcnt(0)" ::: "memory");
  __builtin_amdgcn_s_barrier();

#pragma unroll 1
  for (int p = 0; p < NP; ++p) {
    const int cur = p & 1;
    if (p + 1 < NP) STAGE(p + 1, cur ^ 1);  // prefetch under this phase's compute
#pragma unroll
    for (int st = 0; st < 4; ++st) {
      const char* sb = ldsb + cur * 16384 + st * 4096;
      f32x4 acc[4];
#pragma unroll
      for (int g = 0; g < 4; ++g) acc[g] = (f32x4){0.f, 0.f, 0.f, 0.f};
      __builtin_amdgcn_s_setprio(1);
#pragma unroll
      for (int kk = 0; kk < 4; ++kk) {
        bf16x8 bv = *(const bf16x8*)(sb + rdo[kk]);
#pragma unroll
        for (int g = 0; g < 4; ++g)
          acc[g] = __builtin_amdgcn_mfma_f32_16x16x32_bf16(af[g][kk], bv, acc[g], 0, 0, 0);
      }
      __builtin_amdgcn_s_setprio(0);
      const int gd = cs * 16 + p * 4 + st - RT0;  // diag subtile's g (uniform)
#pragma unroll
      for (int g = 0; g < 4; ++g)
#pragma unroll
        for (int r = 0; r < 4; ++r) {
          float e = fast_exp2(acc[g][r]);
          if (g == gd && lo == hi * 4 + r) e = 0.0f;  // mask self
          sums[g][r] += e;
        }
    }
    asm volatile("s_waitcnt vmcnt(0)" ::: "memory");  // prefetch landed
    __builtin_amdgcn_s_barrier();                     // visible to all waves
  }
#undef STAGE

  // reduce 16 column-slots per row; one atomic per row per wave
#pragma unroll
  for (int g = 0; g < 4; ++g)
#pragma unroll
    for (int r = 0; r < 4; ++r) {
      float v = sums[g][r];
      v += __shfl_xor(v, 1, 64);
      v += __shfl_xor(v, 2, 64);
      v += __shfl_xor(v, 4, 64);
      v += __shfl_xor(v, 8, 64);
      if (lo == 0) atomicAdd(&rowsum[rowbase + g * 16 + hi * 4 + r], v);
    }

  // last-block-done final reduction (proven in round 2)
  __syncthreads();
  __shared__ unsigned slast;
  if (tid == 0) {
    __threadfence();
    slast = atomicAdd(ctr, 1u);
  }
  __syncthreads();
  if (slast == GRID_G - 1) {
    __threadfence();  // acquire side
    float s1 = 0.0f, s2 = 0.0f;
    for (int k = tid; k < TOT; k += 256)
      s1 += fast_log2(__hip_atomic_load(&rowsum[k], __ATOMIC_RELAXED,
                                        __HIP_MEMORY_SCOPE_AGENT));
    for (int k = tid; k < NROW; k += 256) s2 += pos[k];
    float c = s1 * (LN2 / (float)TOT) - s2 * (1.0f / (float)NROW);
#pragma unroll
    for (int m = 32; m >= 1; m >>= 1) c += __shfl_xor(c, m, 64);
    __shared__ float ws4[4];
    if (lane == 0) ws4[wid] = c;
    __syncthreads();
    if (tid == 0) out[0] = ws4[0] + ws4[1] + ws4[2] + ws4[3];
  }
}

extern "C" void kernel_launch(void* const* d_in, const int* in_sizes, int n_in,
                              void* d_out, int out_size, void* d_ws, size_t ws_size,
                              hipStream_t stream) {
  const float* ei = (const float*)d_in[0];
  const float* ej = (const float*)d_in[1];
  float* out = (float*)d_out;
  float* rowsum = (float*)d_ws;                                   // 8192 f32
  float* pos = (float*)((char*)d_ws + TOT * 4);                   // 4096 f32
  unsigned* ctr = (unsigned*)((char*)d_ws + TOT * 4 + NROW * 4);  // 1 u32
  unsigned short* Zp =
      (unsigned short*)((char*)d_ws + TOT * 4 + NROW * 4 + 256);  // 8192x128 bf16

  k_norm<<<NROW / 4, 256, 0, stream>>>(ei, ej, Zp, pos, rowsum, ctr);
  k_gemm<<<GRID_G, 256, 0, stream>>>(Zp, rowsum, pos, ctr, out);
}